// Round 1
// baseline (338.951 us; speedup 1.0000x reference)
//
#include <hip/hip_runtime.h>
#include <stdint.h>

#define V_N    4096
#define B_N    4
#define C_N    128
#define POOL_N 1024   // V_N / POOLING_RATE
#define K_NBR  4

// JAX RNG path: 1 = threefry_partitionable (modern JAX default), 0 = original
#ifndef JAX_PARTITIONABLE
#define JAX_PARTITIONABLE 1
#endif

// ---------------- Threefry-2x32 (20 rounds), exactly as JAX lowers it ----
__device__ __forceinline__ void tf2x32(uint32_t k0, uint32_t k1,
                                       uint32_t x0, uint32_t x1,
                                       uint32_t& o0, uint32_t& o1) {
  uint32_t ks[3] = {k0, k1, k0 ^ k1 ^ 0x1BD11BDAu};
  const int R[5][4] = {{13,15,26,6},{17,29,16,24},{13,15,26,6},{17,29,16,24},{13,15,26,6}};
  x0 += ks[0]; x1 += ks[1];
#pragma unroll
  for (int g = 0; g < 5; ++g) {
#pragma unroll
    for (int r = 0; r < 4; ++r) {
      x0 += x1;
      const int rot = R[g][r];
      x1 = (x1 << rot) | (x1 >> (32 - rot));
      x1 ^= x0;
    }
    x0 += ks[(g + 1) % 3];
    x1 += ks[(g + 2) % 3] + (uint32_t)(g + 1);
  }
  o0 = x0; o1 = x1;
}

// ---------------- Kernel 1: replicate jax.random.permutation(key(42),4096)
// 2 rounds of: split -> random_bits -> stable sort (stable via (bits<<32)|pos
// 64-bit keys, bitonic sort in LDS).
__global__ __launch_bounds__(1024) void perm_kernel(int* __restrict__ perm_out) {
  __shared__ unsigned long long skey[V_N];
  __shared__ int sval[V_N];
  const int tid = threadIdx.x;

  // derive the two subkeys (cheap, computed redundantly per-thread)
  uint32_t k0 = 0u, k1 = 42u;          // jax.random.key(42) -> (0, 42)
  uint32_t sub0[2], sub1[2];
#pragma unroll
  for (int r = 0; r < 2; ++r) {
#if JAX_PARTITIONABLE
    // foldlike split: keys[i] = TF(key, (0, i)); key=keys[0], subkey=keys[1]
    uint32_t n0, n1, s0, s1;
    tf2x32(k0, k1, 0u, 0u, n0, n1);
    tf2x32(k0, k1, 0u, 1u, s0, s1);
    sub0[r] = s0; sub1[r] = s1; k0 = n0; k1 = n1;
#else
    // original split: counts=iota(4) -> blocks (0,2),(1,3);
    // reshape(2,2): key=(A0,B0), subkey=(A1,B1)
    uint32_t a0, a1, b0, b1;
    tf2x32(k0, k1, 0u, 2u, a0, a1);
    tf2x32(k0, k1, 1u, 3u, b0, b1);
    sub0[r] = a1; sub1[r] = b1; k0 = a0; k1 = b0;
#endif
  }

  for (int i = tid; i < V_N; i += 1024) sval[i] = i;

#pragma unroll
  for (int r = 0; r < 2; ++r) {
    __syncthreads();
#if JAX_PARTITIONABLE
    // bits[i] = hi ^ lo of TF(subkey, (hi32(i)=0, lo32(i)=i))
    for (int i = tid; i < V_N; i += 1024) {
      uint32_t h, l;
      tf2x32(sub0[r], sub1[r], 0u, (uint32_t)i, h, l);
      skey[i] = (((unsigned long long)(h ^ l)) << 32) | (uint32_t)i;
    }
#else
    // original: counts=iota(4096) split in halves -> blocks (i, 2048+i)
    for (int i = tid; i < V_N / 2; i += 1024) {
      uint32_t h, l;
      tf2x32(sub0[r], sub1[r], (uint32_t)i, (uint32_t)(V_N / 2 + i), h, l);
      skey[i]           = (((unsigned long long)h) << 32) | (uint32_t)i;
      skey[V_N / 2 + i] = (((unsigned long long)l) << 32) | (uint32_t)(V_N / 2 + i);
    }
#endif
    // bitonic sort ascending on 64-bit keys (distinct -> equals stable sort)
    for (int kk = 2; kk <= V_N; kk <<= 1) {
      for (int j = kk >> 1; j > 0; j >>= 1) {
        __syncthreads();
        for (int i = tid; i < V_N; i += 1024) {
          const int l2 = i ^ j;
          if (l2 > i) {
            unsigned long long ki = skey[i], kl = skey[l2];
            const bool sw = ((i & kk) == 0) ? (ki > kl) : (ki < kl);
            if (sw) {
              skey[i] = kl; skey[l2] = ki;
              int t = sval[i]; sval[i] = sval[l2]; sval[l2] = t;
            }
          }
        }
      }
    }
    __syncthreads();
  }
  for (int i = tid; i < V_N; i += 1024) perm_out[i] = sval[i];
}

// ---------------- Kernel 2: kNN (4 nearest, excl self) for sampled verts --
// dist must match reference fp32 rounding:
//   quad  = (x*x + y*y) + z*z                (plain rounds, no contraction)
//   inner = fmaf(z,z', fmaf(y,y', x*x'))     (Eigen-style FMA chain)
//   dist  = ((-2*inner) + quad_m) + quad_n   (fmaf(-2,..) exact: *2 is exact)
// Tie-break: lower index wins (strict-< insertion, ascending m scan).
__global__ __launch_bounds__(256) void knn_kernel(const float* __restrict__ verts,
                                                  const int* __restrict__ perm,
                                                  int* __restrict__ nbr) {
  __shared__ float sx[V_N], sy[V_N], sz[V_N];
  __shared__ float md[64 * 16];
  __shared__ int   mi[64 * 16];
  const int tid = threadIdx.x;
  const int b = blockIdx.y;
  const float* vb = verts + (size_t)b * V_N * 3;

  for (int i = tid; i < V_N * 3; i += 256) {
    const float v = vb[i];
    const int n = i / 3;
    const int d = i - n * 3;
    if (d == 0) sx[n] = v; else if (d == 1) sy[n] = v; else sz[n] = v;
  }
  __syncthreads();

  const int lq  = tid & 63;   // query slot within block (wave lane)
  const int seg = tid >> 6;   // candidate segment = wave id (uniform per wave)
  const int qid = blockIdx.x * 64 + lq;       // 0..1023 output slot
  const int q = perm[qid];                    // sampled vertex index
  const float qx = sx[q], qy = sy[q], qz = sz[q];
  const float qq = __fadd_rn(__fadd_rn(__fmul_rn(qx, qx), __fmul_rn(qy, qy)),
                             __fmul_rn(qz, qz));

  float bd0 = 1e30f, bd1 = 1e30f, bd2 = 1e30f, bd3 = 1e30f;
  int   bi0 = -1, bi1 = -1, bi2 = -1, bi3 = -1;

  const int m0 = seg * (V_N / 4);
  for (int m = m0; m < m0 + V_N / 4; ++m) {
    const float x = sx[m], y = sy[m], z = sz[m];  // uniform addr -> broadcast
    const float qm = __fadd_rn(__fadd_rn(__fmul_rn(x, x), __fmul_rn(y, y)),
                               __fmul_rn(z, z));
    const float inner = __fmaf_rn(qz, z, __fmaf_rn(qy, y, __fmul_rn(qx, x)));
    const float dist = __fadd_rn(__fmaf_rn(-2.0f, inner, qm), qq);
    if (m == q) continue;                     // reference drops self (rank 0)
    if (dist < bd3) {
      if (dist < bd2) {
        bd3 = bd2; bi3 = bi2;
        if (dist < bd1) {
          bd2 = bd1; bi2 = bi1;
          if (dist < bd0) { bd1 = bd0; bi1 = bi0; bd0 = dist; bi0 = m; }
          else            { bd1 = dist; bi1 = m; }
        } else { bd2 = dist; bi2 = m; }
      } else { bd3 = dist; bi3 = m; }
    }
  }

  const int base = (lq * 4 + seg) * 4;
  md[base + 0] = bd0; md[base + 1] = bd1; md[base + 2] = bd2; md[base + 3] = bd3;
  mi[base + 0] = bi0; mi[base + 1] = bi1; mi[base + 2] = bi2; mi[base + 3] = bi3;
  __syncthreads();

  if (seg == 0) {
    // merge 4 sorted 4-lists lexicographically by (dist, idx)
    int p[4] = {0, 0, 0, 0};
    const int ob = ((b * POOL_N) + qid) * 4;
    for (int o = 0; o < 4; ++o) {
      float best = 1e38f; int besti = 0x7fffffff; int bs = 0;
#pragma unroll
      for (int s = 0; s < 4; ++s) {
        const float dd = md[(lq * 4 + s) * 4 + p[s]];
        const int   ii = mi[(lq * 4 + s) * 4 + p[s]];
        if (dd < best || (dd == best && ii < besti)) { best = dd; besti = ii; bs = s; }
      }
      p[bs]++;
      nbr[ob + o] = besti;
    }
  }
}

// ---------------- Kernel 3: vertices_pool gather (exact) ------------------
__global__ __launch_bounds__(256) void vgather_kernel(const float* __restrict__ verts,
                                                      const int* __restrict__ perm,
                                                      float* __restrict__ outV) {
  const int t = blockIdx.x * 256 + threadIdx.x;
  if (t >= B_N * POOL_N * 3) return;
  const int d = t % 3;
  const int r = t / 3;
  const int j = r & (POOL_N - 1);
  const int b = r >> 10;
  outV[t] = verts[((size_t)b * V_N + perm[j]) * 3 + d];
}

// ---------------- Kernel 4: feature max-pool over 4 neighbors (exact) -----
__global__ __launch_bounds__(256) void pool_kernel(const float* __restrict__ fm,
                                                   const int* __restrict__ nbr,
                                                   float* __restrict__ outF) {
  const int t = blockIdx.x * 256 + threadIdx.x;
  if (t >= B_N * C_N * POOL_N) return;
  const int j  = t & (POOL_N - 1);
  const int bc = t >> 10;          // b*128 + c
  const int b  = bc >> 7;
  const int* nb = nbr + ((b * POOL_N) + j) * 4;
  const float* base = fm + (size_t)bc * V_N * 3;
  const float* p0 = base + nb[0] * 3;
  const float* p1 = base + nb[1] * 3;
  const float* p2 = base + nb[2] * 3;
  const float* p3 = base + nb[3] * 3;
  const float m0 = fmaxf(fmaxf(p0[0], p1[0]), fmaxf(p2[0], p3[0]));
  const float m1 = fmaxf(fmaxf(p0[1], p1[1]), fmaxf(p2[1], p3[1]));
  const float m2 = fmaxf(fmaxf(p0[2], p1[2]), fmaxf(p2[2], p3[2]));
  float* o = outF + (size_t)t * 3;
  o[0] = m0; o[1] = m1; o[2] = m2;
}

extern "C" void kernel_launch(void* const* d_in, const int* in_sizes, int n_in,
                              void* d_out, int out_size, void* d_ws, size_t ws_size,
                              hipStream_t stream) {
  const float* verts = (const float*)d_in[0];   // (4, 4096, 3) f32
  const float* fm    = (const float*)d_in[1];   // (4, 128, 4096, 3) f32
  float* out = (float*)d_out;                   // 12288 + 1572864 f32
  int* perm = (int*)d_ws;                       // [4096]
  int* nbr  = perm + V_N;                       // [4*1024*4]

  perm_kernel<<<1, 1024, 0, stream>>>(perm);
  knn_kernel<<<dim3(POOL_N / 64, B_N), 256, 0, stream>>>(verts, perm, nbr);
  vgather_kernel<<<(B_N * POOL_N * 3 + 255) / 256, 256, 0, stream>>>(verts, perm, out);
  pool_kernel<<<(B_N * C_N * POOL_N + 255) / 256, 256, 0, stream>>>(fm, nbr, out + B_N * POOL_N * 3);
}

// Round 2
// 204.701 us; speedup vs baseline: 1.6558x; 1.6558x over previous
//
#include <hip/hip_runtime.h>
#include <stdint.h>

#define V_N    4096
#define B_N    4
#define C_N    128
#define POOL_N 1024   // V_N / POOLING_RATE
#define K_NBR  4

// ---------------- Threefry-2x32 (20 rounds), exactly as JAX lowers it ----
// (host+device: subkey derivation runs on CPU in kernel_launch)
__host__ __device__ __forceinline__ void tf2x32(uint32_t k0, uint32_t k1,
                                                uint32_t x0, uint32_t x1,
                                                uint32_t& o0, uint32_t& o1) {
  uint32_t ks[3] = {k0, k1, k0 ^ k1 ^ 0x1BD11BDAu};
  const int R[5][4] = {{13,15,26,6},{17,29,16,24},{13,15,26,6},{17,29,16,24},{13,15,26,6}};
  x0 += ks[0]; x1 += ks[1];
#pragma unroll
  for (int g = 0; g < 5; ++g) {
#pragma unroll
    for (int r = 0; r < 4; ++r) {
      x0 += x1;
      const int rot = R[g][r];
      x1 = (x1 << rot) | (x1 >> (32 - rot));
      x1 ^= x0;
    }
    x0 += ks[(g + 1) % 3];
    x1 += ks[(g + 2) % 3] + (uint32_t)(g + 1);
  }
  o0 = x0; o1 = x1;
}

// ---------------- Kernel 1: one permutation round via rank counting-sort --
// Stable sort of distinct keys (bits<<32)|pos == counting sort by rank.
// 64 blocks x 256 threads; wave w scans candidate segment w (uniform j ->
// LDS broadcast, conflict-free); partial ranks reduced in LDS; scatter.
__global__ __launch_bounds__(256) void rank_perm_kernel(uint32_t s0, uint32_t s1,
                                                        const int* __restrict__ vals_in,
                                                        int* __restrict__ vals_out) {
  __shared__ unsigned long long skey[V_N];   // 32 KB
  __shared__ int partial[64][4];
  const int tid = threadIdx.x;

  // generate this round's keys: bits[i] = hi^lo of TF(subkey, (0, i))
  for (int i = tid; i < V_N; i += 256) {
    uint32_t h, l;
    tf2x32(s0, s1, 0u, (uint32_t)i, h, l);
    skey[i] = (((unsigned long long)(h ^ l)) << 32) | (uint32_t)i;
  }
  __syncthreads();

  const int q   = tid & 63;                 // query slot (lane)
  const int seg = tid >> 6;                 // candidate segment (wave id)
  const int e   = blockIdx.x * 64 + q;      // element position 0..4095
  const unsigned long long mykey = skey[e];

  int rank = 0;
  const int j0 = seg * (V_N / 4);
#pragma unroll 8
  for (int j = j0; j < j0 + V_N / 4; ++j)
    rank += (skey[j] < mykey) ? 1 : 0;      // skey[j] wave-uniform -> broadcast

  partial[q][seg] = rank;
  __syncthreads();

  if (seg == 0) {
    const int r = partial[q][0] + partial[q][1] + partial[q][2] + partial[q][3];
    vals_out[r] = vals_in ? vals_in[e] : e; // round 1: identity values
  }
}

// ---------------- Kernel 2: kNN (4 nearest, excl self) for sampled verts --
// dist must match reference fp32 rounding:
//   quad  = (x*x + y*y) + z*z                (plain rounds, no contraction)
//   inner = fmaf(z,z', fmaf(y,y', x*x'))     (Eigen-style FMA chain)
//   dist  = ((-2*inner) + quad_m) + quad_n
// Tie-break: lower index wins (strict-< insertion, ascending m scan).
__global__ __launch_bounds__(256) void knn_kernel(const float* __restrict__ verts,
                                                  const int* __restrict__ perm,
                                                  int* __restrict__ nbr) {
  __shared__ float sx[V_N], sy[V_N], sz[V_N];
  __shared__ float md[64 * 16];
  __shared__ int   mi[64 * 16];
  const int tid = threadIdx.x;
  const int b = blockIdx.y;
  const float* vb = verts + (size_t)b * V_N * 3;

  for (int i = tid; i < V_N * 3; i += 256) {
    const float v = vb[i];
    const int n = i / 3;
    const int d = i - n * 3;
    if (d == 0) sx[n] = v; else if (d == 1) sy[n] = v; else sz[n] = v;
  }
  __syncthreads();

  const int lq  = tid & 63;   // query slot within block (wave lane)
  const int seg = tid >> 6;   // candidate segment = wave id (uniform per wave)
  const int qid = blockIdx.x * 64 + lq;       // 0..1023 output slot
  const int q = perm[qid];                    // sampled vertex index
  const float qx = sx[q], qy = sy[q], qz = sz[q];
  const float qq = __fadd_rn(__fadd_rn(__fmul_rn(qx, qx), __fmul_rn(qy, qy)),
                             __fmul_rn(qz, qz));

  float bd0 = 1e30f, bd1 = 1e30f, bd2 = 1e30f, bd3 = 1e30f;
  int   bi0 = -1, bi1 = -1, bi2 = -1, bi3 = -1;

  const int m0 = seg * (V_N / 4);
  for (int m = m0; m < m0 + V_N / 4; ++m) {
    const float x = sx[m], y = sy[m], z = sz[m];  // uniform addr -> broadcast
    const float qm = __fadd_rn(__fadd_rn(__fmul_rn(x, x), __fmul_rn(y, y)),
                               __fmul_rn(z, z));
    const float inner = __fmaf_rn(qz, z, __fmaf_rn(qy, y, __fmul_rn(qx, x)));
    const float dist = __fadd_rn(__fmaf_rn(-2.0f, inner, qm), qq);
    if (m == q) continue;                     // reference drops self (rank 0)
    if (dist < bd3) {
      if (dist < bd2) {
        bd3 = bd2; bi3 = bi2;
        if (dist < bd1) {
          bd2 = bd1; bi2 = bi1;
          if (dist < bd0) { bd1 = bd0; bi1 = bi0; bd0 = dist; bi0 = m; }
          else            { bd1 = dist; bi1 = m; }
        } else { bd2 = dist; bi2 = m; }
      } else { bd3 = dist; bi3 = m; }
    }
  }

  const int base = (lq * 4 + seg) * 4;
  md[base + 0] = bd0; md[base + 1] = bd1; md[base + 2] = bd2; md[base + 3] = bd3;
  mi[base + 0] = bi0; mi[base + 1] = bi1; mi[base + 2] = bi2; mi[base + 3] = bi3;
  __syncthreads();

  if (seg == 0) {
    // merge 4 sorted 4-lists lexicographically by (dist, idx)
    int p[4] = {0, 0, 0, 0};
    const int ob = ((b * POOL_N) + qid) * 4;
    for (int o = 0; o < 4; ++o) {
      float best = 1e38f; int besti = 0x7fffffff; int bs = 0;
#pragma unroll
      for (int s = 0; s < 4; ++s) {
        const float dd = md[(lq * 4 + s) * 4 + p[s]];
        const int   ii = mi[(lq * 4 + s) * 4 + p[s]];
        if (dd < best || (dd == best && ii < besti)) { best = dd; besti = ii; bs = s; }
      }
      p[bs]++;
      nbr[ob + o] = besti;
    }
  }
}

// ---------------- Kernel 3: vertices_pool gather (exact) ------------------
__global__ __launch_bounds__(256) void vgather_kernel(const float* __restrict__ verts,
                                                      const int* __restrict__ perm,
                                                      float* __restrict__ outV) {
  const int t = blockIdx.x * 256 + threadIdx.x;
  if (t >= B_N * POOL_N * 3) return;
  const int d = t % 3;
  const int r = t / 3;
  const int j = r & (POOL_N - 1);
  const int b = r >> 10;
  outV[t] = verts[((size_t)b * V_N + perm[j]) * 3 + d];
}

// ---------------- Kernel 4: feature max-pool over 4 neighbors (exact) -----
__global__ __launch_bounds__(256) void pool_kernel(const float* __restrict__ fm,
                                                   const int* __restrict__ nbr,
                                                   float* __restrict__ outF) {
  const int t = blockIdx.x * 256 + threadIdx.x;
  if (t >= B_N * C_N * POOL_N) return;
  const int j  = t & (POOL_N - 1);
  const int bc = t >> 10;          // b*128 + c
  const int b  = bc >> 7;
  const int4 nb = *(const int4*)(nbr + ((b * POOL_N) + j) * 4);
  const float* base = fm + (size_t)bc * V_N * 3;
  const float* p0 = base + nb.x * 3;
  const float* p1 = base + nb.y * 3;
  const float* p2 = base + nb.z * 3;
  const float* p3 = base + nb.w * 3;
  const float m0 = fmaxf(fmaxf(p0[0], p1[0]), fmaxf(p2[0], p3[0]));
  const float m1 = fmaxf(fmaxf(p0[1], p1[1]), fmaxf(p2[1], p3[1]));
  const float m2 = fmaxf(fmaxf(p0[2], p1[2]), fmaxf(p2[2], p3[2]));
  float* o = outF + (size_t)t * 3;
  o[0] = m0; o[1] = m1; o[2] = m2;
}

extern "C" void kernel_launch(void* const* d_in, const int* in_sizes, int n_in,
                              void* d_out, int out_size, void* d_ws, size_t ws_size,
                              hipStream_t stream) {
  const float* verts = (const float*)d_in[0];   // (4, 4096, 3) f32
  const float* fm    = (const float*)d_in[1];   // (4, 128, 4096, 3) f32
  float* out = (float*)d_out;                   // 12288 + 1572864 f32
  int* perm_a = (int*)d_ws;                     // [4096] round-1 result
  int* perm_b = perm_a + V_N;                   // [4096] final permutation
  int* nbr    = perm_b + V_N;                   // [4*1024*4]

  // Derive the two round subkeys on host (pure CPU arithmetic, deterministic;
  // baked into the graph as kernel args).  key(42) = (0, 42); foldlike split:
  // next_key = TF(key,(0,0)), subkey = TF(key,(0,1)).
  uint32_t k0 = 0u, k1 = 42u, sub0[2], sub1[2];
  for (int r = 0; r < 2; ++r) {
    uint32_t n0, n1, s0, s1;
    tf2x32(k0, k1, 0u, 0u, n0, n1);
    tf2x32(k0, k1, 0u, 1u, s0, s1);
    sub0[r] = s0; sub1[r] = s1; k0 = n0; k1 = n1;
  }

  rank_perm_kernel<<<64, 256, 0, stream>>>(sub0[0], sub1[0], nullptr, perm_a);
  rank_perm_kernel<<<64, 256, 0, stream>>>(sub0[1], sub1[1], perm_a, perm_b);
  knn_kernel<<<dim3(POOL_N / 64, B_N), 256, 0, stream>>>(verts, perm_b, nbr);
  vgather_kernel<<<(B_N * POOL_N * 3 + 255) / 256, 256, 0, stream>>>(verts, perm_b, out);
  pool_kernel<<<(B_N * C_N * POOL_N + 255) / 256, 256, 0, stream>>>(fm, nbr, out + B_N * POOL_N * 3);
}

// Round 3
// 103.543 us; speedup vs baseline: 3.2735x; 1.9770x over previous
//
#include <hip/hip_runtime.h>
#include <stdint.h>

#define V_N    4096
#define B_N    4
#define C_N    128
#define POOL_N 1024   // V_N / POOLING_RATE
#define K_NBR  4

// ---------------- Threefry-2x32 (20 rounds), exactly as JAX lowers it ----
__host__ __device__ __forceinline__ void tf2x32(uint32_t k0, uint32_t k1,
                                                uint32_t x0, uint32_t x1,
                                                uint32_t& o0, uint32_t& o1) {
  uint32_t ks[3] = {k0, k1, k0 ^ k1 ^ 0x1BD11BDAu};
  const int R[5][4] = {{13,15,26,6},{17,29,16,24},{13,15,26,6},{17,29,16,24},{13,15,26,6}};
  x0 += ks[0]; x1 += ks[1];
#pragma unroll
  for (int g = 0; g < 5; ++g) {
#pragma unroll
    for (int r = 0; r < 4; ++r) {
      x0 += x1;
      const int rot = R[g][r];
      x1 = (x1 << rot) | (x1 >> (32 - rot));
      x1 ^= x0;
    }
    x0 += ks[(g + 1) % 3];
    x1 += ks[(g + 2) % 3] + (uint32_t)(g + 1);
  }
  o0 = x0; o1 = x1;
}

// ---------------- Kernel 1: full 2-round permutation, one launch ----------
// Stable sort of distinct (bits, idx) pairs == counting sort by rank, and
// final[r2(r1(i))] = i, where r1/r2 depend only on the fixed keys. Thread
// for element e: scan keys1 -> p = r1(e); scan keys2 vs (bits2[p], p) -> r2;
// write final[r2] = e.  16 elems x 16 interleaved segments per block.
__global__ __launch_bounds__(256) void perm_kernel(uint32_t s10, uint32_t s11,
                                                   uint32_t s20, uint32_t s21,
                                                   int* __restrict__ final_perm) {
  __shared__ uint32_t b1[V_N];        // 16 KB round-1 bits
  __shared__ uint32_t b2[V_N];        // 16 KB round-2 bits
  __shared__ int partial[16][16];     // [seg][q]
  __shared__ int pbuf[16];
  __shared__ uint32_t kbuf[16];
  const int tid = threadIdx.x;

  // keygen: bits[i] = hi ^ lo of TF(subkey, (0, i)); 32 TF per thread
#pragma unroll
  for (int w = 0; w < 16; ++w) {
    const int i = tid + 256 * w;
    uint32_t h, l;
    tf2x32(s10, s11, 0u, (uint32_t)i, h, l); b1[i] = h ^ l;
    tf2x32(s20, s21, 0u, (uint32_t)i, h, l); b2[i] = h ^ l;
  }
  __syncthreads();

  const int q   = tid & 15;            // element slot in block
  const int seg = tid >> 4;            // candidate segment
  const int e   = blockIdx.x * 16 + q; // element 0..4095
  const uint32_t ke = b1[e];

  // scan 1: rank of (b1[e], e) among all (b1[m], m)
  int r = 0;
#pragma unroll 8
  for (int i = 0; i < 256; ++i) {
    const int m = seg + 16 * i;        // 4 distinct banks per wave, broadcast
    const uint32_t bm = b1[m];
    r += (bm < ke || (bm == ke && m < e)) ? 1 : 0;
  }
  partial[seg][q] = r;
  __syncthreads();
  if (tid < 16) {
    int p = 0;
#pragma unroll
    for (int s = 0; s < 16; ++s) p += partial[s][tid];
    pbuf[tid] = p;
    kbuf[tid] = b2[p];
  }
  __syncthreads();

  // scan 2: rank of (b2[p], p) among all (b2[m], m)
  const int p = pbuf[q];
  const uint32_t kp = kbuf[q];
  r = 0;
#pragma unroll 8
  for (int i = 0; i < 256; ++i) {
    const int m = seg + 16 * i;
    const uint32_t bm = b2[m];
    r += (bm < kp || (bm == kp && m < p)) ? 1 : 0;
  }
  partial[seg][q] = r;
  __syncthreads();
  if (tid < 16) {
    int r2 = 0;
#pragma unroll
    for (int s = 0; s < 16; ++s) r2 += partial[s][tid];
    final_perm[r2] = blockIdx.x * 16 + tid;
  }
}

// ---------------- Kernel 2: kNN (4 nearest, excl self) + fused vgather ----
// 16 queries x 16 interleaved candidate segments per 256-thread block.
// dist replicates reference fp32 rounding exactly (see round-0 notes).
__global__ __launch_bounds__(256) void knn_kernel(const float* __restrict__ verts,
                                                  const int* __restrict__ perm,
                                                  int* __restrict__ nbr,
                                                  float* __restrict__ outV) {
  __shared__ float sx[V_N], sy[V_N], sz[V_N];   // 48 KB
  __shared__ float md[16 * 16 * 4];             // [seg][q][4]
  __shared__ int   mi[16 * 16 * 4];
  const int tid = threadIdx.x;
  const int b = blockIdx.y;
  const float* vb = verts + (size_t)b * V_N * 3;

  for (int i = tid; i < V_N * 3; i += 256) {
    const float v = vb[i];
    const int n = i / 3;
    const int d = i - n * 3;
    if (d == 0) sx[n] = v; else if (d == 1) sy[n] = v; else sz[n] = v;
  }
  __syncthreads();

  const int lq  = tid & 15;
  const int seg = tid >> 4;
  const int qid = blockIdx.x * 16 + lq;        // 0..1023 output slot
  const int qv = perm[qid];                    // sampled vertex index
  const float qx = sx[qv], qy = sy[qv], qz = sz[qv];
  const float qq = __fadd_rn(__fadd_rn(__fmul_rn(qx, qx), __fmul_rn(qy, qy)),
                             __fmul_rn(qz, qz));

  float bd0 = 1e30f, bd1 = 1e30f, bd2 = 1e30f, bd3 = 1e30f;
  int   bi0 = -1, bi1 = -1, bi2 = -1, bi3 = -1;

#pragma unroll 4
  for (int i = 0; i < 256; ++i) {
    const int m = seg + 16 * i;                 // 4 distinct banks per wave
    const float x = sx[m], y = sy[m], z = sz[m];
    const float qm = __fadd_rn(__fadd_rn(__fmul_rn(x, x), __fmul_rn(y, y)),
                               __fmul_rn(z, z));
    const float inner = __fmaf_rn(qz, z, __fmaf_rn(qy, y, __fmul_rn(qx, x)));
    const float dist = __fadd_rn(__fmaf_rn(-2.0f, inner, qm), qq);
    if (m == qv) continue;                      // reference drops self (rank 0)
    if (dist < bd3) {
      if (dist < bd2) {
        bd3 = bd2; bi3 = bi2;
        if (dist < bd1) {
          bd2 = bd1; bi2 = bi1;
          if (dist < bd0) { bd1 = bd0; bi1 = bi0; bd0 = dist; bi0 = m; }
          else            { bd1 = dist; bi1 = m; }
        } else { bd2 = dist; bi2 = m; }
      } else { bd3 = dist; bi3 = m; }
    }
  }

  const int base = (seg * 16 + lq) * 4;
  md[base + 0] = bd0; md[base + 1] = bd1; md[base + 2] = bd2; md[base + 3] = bd3;
  mi[base + 0] = bi0; mi[base + 1] = bi1; mi[base + 2] = bi2; mi[base + 3] = bi3;
  __syncthreads();

  if (tid < 16) {
    // top-4 of the union of 64 entries: 4 rounds of lexicographic-min with
    // picked-index exclusion (indices unique across segments; register-only)
    int p0 = -1, p1 = -1, p2 = -1, p3 = -1;
    const int ob = ((b * POOL_N) + blockIdx.x * 16 + tid) * 4;
    for (int o = 0; o < 4; ++o) {
      float best = 1e38f; int besti = 0x7fffffff;
      for (int s = 0; s < 16; ++s) {
#pragma unroll
        for (int k = 0; k < 4; ++k) {
          const float dd = md[(s * 16 + tid) * 4 + k];
          const int   ii = mi[(s * 16 + tid) * 4 + k];
          if (ii == p0 || ii == p1 || ii == p2 || ii == p3) continue;
          if (dd < best || (dd == best && ii < besti)) { best = dd; besti = ii; }
        }
      }
      if      (o == 0) p0 = besti;
      else if (o == 1) p1 = besti;
      else if (o == 2) p2 = besti;
      else             p3 = besti;
      nbr[ob + o] = besti;
    }
  }

  // fused vertices_pool gather: 16 queries x 3 dims
  if (tid < 48) {
    const int qid2 = blockIdx.x * 16 + tid / 3;
    const int d = tid % 3;
    const int v = perm[qid2];
    const float val = (d == 0) ? sx[v] : (d == 1) ? sy[v] : sz[v];
    outV[((size_t)b * POOL_N + qid2) * 3 + d] = val;
  }
}

// ---------------- Kernel 3: feature max-pool over 4 neighbors (exact) -----
__global__ __launch_bounds__(256) void pool_kernel(const float* __restrict__ fm,
                                                   const int* __restrict__ nbr,
                                                   float* __restrict__ outF) {
  const int t = blockIdx.x * 256 + threadIdx.x;
  if (t >= B_N * C_N * POOL_N) return;
  const int j  = t & (POOL_N - 1);
  const int bc = t >> 10;          // b*128 + c
  const int b  = bc >> 7;
  const int4 nb = *(const int4*)(nbr + ((b * POOL_N) + j) * 4);
  const float* base = fm + (size_t)bc * V_N * 3;
  const float* p0 = base + nb.x * 3;
  const float* p1 = base + nb.y * 3;
  const float* p2 = base + nb.z * 3;
  const float* p3 = base + nb.w * 3;
  const float m0 = fmaxf(fmaxf(p0[0], p1[0]), fmaxf(p2[0], p3[0]));
  const float m1 = fmaxf(fmaxf(p0[1], p1[1]), fmaxf(p2[1], p3[1]));
  const float m2 = fmaxf(fmaxf(p0[2], p1[2]), fmaxf(p2[2], p3[2]));
  float* o = outF + (size_t)t * 3;
  o[0] = m0; o[1] = m1; o[2] = m2;
}

extern "C" void kernel_launch(void* const* d_in, const int* in_sizes, int n_in,
                              void* d_out, int out_size, void* d_ws, size_t ws_size,
                              hipStream_t stream) {
  const float* verts = (const float*)d_in[0];   // (4, 4096, 3) f32
  const float* fm    = (const float*)d_in[1];   // (4, 128, 4096, 3) f32
  float* out = (float*)d_out;                   // 12288 + 1572864 f32
  int* perm = (int*)d_ws;                       // [4096]
  int* nbr  = perm + V_N;                       // [4*1024*4]

  // Derive both rounds' subkeys on host (deterministic, baked as kernel args).
  // key(42) = (0, 42); foldlike split: next = TF(key,(0,0)), sub = TF(key,(0,1)).
  uint32_t k0 = 0u, k1 = 42u, sub0[2], sub1[2];
  for (int r = 0; r < 2; ++r) {
    uint32_t n0, n1, s0, s1;
    tf2x32(k0, k1, 0u, 0u, n0, n1);
    tf2x32(k0, k1, 0u, 1u, s0, s1);
    sub0[r] = s0; sub1[r] = s1; k0 = n0; k1 = n1;
  }

  perm_kernel<<<V_N / 16, 256, 0, stream>>>(sub0[0], sub1[0], sub0[1], sub1[1], perm);
  knn_kernel<<<dim3(POOL_N / 16, B_N), 256, 0, stream>>>(verts, perm, nbr, out);
  pool_kernel<<<(B_N * C_N * POOL_N + 255) / 256, 256, 0, stream>>>(fm, nbr, out + B_N * POOL_N * 3);
}

// Round 4
// 57.304 us; speedup vs baseline: 5.9150x; 1.8069x over previous
//
#include <hip/hip_runtime.h>
#include <stdint.h>

#define V_N    4096
#define B_N    4
#define C_N    128
#define POOL_N 1024   // V_N / POOLING_RATE
#define K_NBR  4

// ---------------- Threefry-2x32 (20 rounds), exactly as JAX lowers it ----
__host__ __device__ __forceinline__ void tf2x32(uint32_t k0, uint32_t k1,
                                                uint32_t x0, uint32_t x1,
                                                uint32_t& o0, uint32_t& o1) {
  uint32_t ks[3] = {k0, k1, k0 ^ k1 ^ 0x1BD11BDAu};
  const int R[5][4] = {{13,15,26,6},{17,29,16,24},{13,15,26,6},{17,29,16,24},{13,15,26,6}};
  x0 += ks[0]; x1 += ks[1];
#pragma unroll
  for (int g = 0; g < 5; ++g) {
#pragma unroll
    for (int r = 0; r < 4; ++r) {
      x0 += x1;
      const int rot = R[g][r];
      x1 = (x1 << rot) | (x1 >> (32 - rot));
      x1 ^= x0;
    }
    x0 += ks[(g + 1) % 3];
    x1 += ks[(g + 2) % 3] + (uint32_t)(g + 1);
  }
  o0 = x0; o1 = x1;
}

// ---------------- Kernel 1: full 2-round permutation, one launch ----------
// Stable sort of distinct (bits, idx) pairs == counting sort by rank, and
// final[r2(r1(i))] = i, where r1/r2 depend only on the fixed keys.
__global__ __launch_bounds__(256) void perm_kernel(uint32_t s10, uint32_t s11,
                                                   uint32_t s20, uint32_t s21,
                                                   int* __restrict__ final_perm) {
  __shared__ uint32_t b1[V_N];        // 16 KB round-1 bits
  __shared__ uint32_t b2[V_N];        // 16 KB round-2 bits
  __shared__ int partial[16][16];     // [seg][q]
  __shared__ int pbuf[16];
  __shared__ uint32_t kbuf[16];
  const int tid = threadIdx.x;

#pragma unroll
  for (int w = 0; w < 16; ++w) {
    const int i = tid + 256 * w;
    uint32_t h, l;
    tf2x32(s10, s11, 0u, (uint32_t)i, h, l); b1[i] = h ^ l;
    tf2x32(s20, s21, 0u, (uint32_t)i, h, l); b2[i] = h ^ l;
  }
  __syncthreads();

  const int q   = tid & 15;            // element slot in block
  const int seg = tid >> 4;            // candidate segment
  const int e   = blockIdx.x * 16 + q; // element 0..4095
  const uint32_t ke = b1[e];

  int r = 0;
#pragma unroll 8
  for (int i = 0; i < 256; ++i) {
    const int m = seg + 16 * i;
    const uint32_t bm = b1[m];
    r += (bm < ke || (bm == ke && m < e)) ? 1 : 0;
  }
  partial[seg][q] = r;
  __syncthreads();
  if (tid < 16) {
    int p = 0;
#pragma unroll
    for (int s = 0; s < 16; ++s) p += partial[s][tid];
    pbuf[tid] = p;
    kbuf[tid] = b2[p];
  }
  __syncthreads();

  const int p = pbuf[q];
  const uint32_t kp = kbuf[q];
  r = 0;
#pragma unroll 8
  for (int i = 0; i < 256; ++i) {
    const int m = seg + 16 * i;
    const uint32_t bm = b2[m];
    r += (bm < kp || (bm == kp && m < p)) ? 1 : 0;
  }
  partial[seg][q] = r;
  __syncthreads();
  if (tid < 16) {
    int r2 = 0;
#pragma unroll
    for (int s = 0; s < 16; ++s) r2 += partial[s][tid];
    final_perm[r2] = blockIdx.x * 16 + tid;
  }
}

// ---------------- Kernel 2: kNN, one query per WAVE + shuffle merge -------
// dist replicates reference fp32 rounding exactly:
//   quad  = (x*x + y*y) + z*z ; inner = fmaf(z,z',fmaf(y,y',x*x'))
//   dist  = ((-2*inner) + quad_m) + quad_n
// Selection: lexicographic (dist, idx) top-4 excluding self — identical
// semantics to lax.top_k(-dist, 5)[1:].
__device__ __forceinline__ bool lexlt(float d1, int i1, float d2, int i2) {
  return d1 < d2 || (d1 == d2 && i1 < i2);
}
__device__ __forceinline__ void ce(float& da, int& ia, float& db, int& ib) {
  if (!lexlt(da, ia, db, ib)) {
    float td = da; da = db; db = td;
    int   ti = ia; ia = ib; ib = ti;
  }
}

__global__ __launch_bounds__(512) void knn_kernel(const float* __restrict__ verts,
                                                  const int* __restrict__ perm,
                                                  int* __restrict__ nbr,
                                                  float* __restrict__ outV) {
  __shared__ float sv[V_N * 3];                 // 48 KB packed xyz
  const int tid = threadIdx.x;
  const int b = blockIdx.y;
  const float4* vb4 = (const float4*)(verts + (size_t)b * V_N * 3);
#pragma unroll
  for (int w = 0; w < 6; ++w)
    ((float4*)sv)[tid + 512 * w] = vb4[tid + 512 * w];
  __syncthreads();

  const int lane = tid & 63;
  const int wv   = tid >> 6;                    // wave id 0..7 = query slot
  const int qid  = blockIdx.x * 8 + wv;         // 0..1023 output slot
  const int qv   = perm[qid];                   // sampled vertex index
  const float qx = sv[3 * qv], qy = sv[3 * qv + 1], qz = sv[3 * qv + 2];
  const float qq = __fadd_rn(__fadd_rn(__fmul_rn(qx, qx), __fmul_rn(qy, qy)),
                             __fmul_rn(qz, qz));

  float bd0 = 1e30f, bd1 = 1e30f, bd2 = 1e30f, bd3 = 1e30f;
  int   bi0 = -1, bi1 = -1, bi2 = -1, bi3 = -1;

#pragma unroll 4
  for (int i = 0; i < 64; ++i) {
    const int m = lane + 64 * i;                // interleaved: 2-way LDS alias (free)
    const float x = sv[3 * m], y = sv[3 * m + 1], z = sv[3 * m + 2];
    const float qm = __fadd_rn(__fadd_rn(__fmul_rn(x, x), __fmul_rn(y, y)),
                               __fmul_rn(z, z));
    const float inner = __fmaf_rn(qz, z, __fmaf_rn(qy, y, __fmul_rn(qx, x)));
    const float dist = __fadd_rn(__fmaf_rn(-2.0f, inner, qm), qq);
    if (m == qv) continue;                      // reference drops self (rank 0)
    if (dist < bd3) {
      if (dist < bd2) {
        bd3 = bd2; bi3 = bi2;
        if (dist < bd1) {
          bd2 = bd1; bi2 = bi1;
          if (dist < bd0) { bd1 = bd0; bi1 = bi0; bd0 = dist; bi0 = m; }
          else            { bd1 = dist; bi1 = m; }
        } else { bd2 = dist; bi2 = m; }
      } else { bd3 = dist; bi3 = m; }
    }
  }

  // 6-stage butterfly: merge two sorted 4-lists -> sorted top-4 (bitonic).
#pragma unroll
  for (int off = 1; off <= 32; off <<= 1) {
    const float e0 = __shfl_xor(bd0, off), e1 = __shfl_xor(bd1, off);
    const float e2 = __shfl_xor(bd2, off), e3 = __shfl_xor(bd3, off);
    const int   f0 = __shfl_xor(bi0, off), f1 = __shfl_xor(bi1, off);
    const int   f2 = __shfl_xor(bi2, off), f3 = __shfl_xor(bi3, off);
    // lower bitonic half of [bd0..bd3, e3..e0]: reversed elementwise min
    const bool c0 = lexlt(bd0, bi0, e3, f3); bd0 = c0 ? bd0 : e3; bi0 = c0 ? bi0 : f3;
    const bool c1 = lexlt(bd1, bi1, e2, f2); bd1 = c1 ? bd1 : e2; bi1 = c1 ? bi1 : f2;
    const bool c2 = lexlt(bd2, bi2, e1, f1); bd2 = c2 ? bd2 : e1; bi2 = c2 ? bi2 : f1;
    const bool c3 = lexlt(bd3, bi3, e0, f0); bd3 = c3 ? bd3 : e0; bi3 = c3 ? bi3 : f0;
    // bitonic sort-4
    ce(bd0, bi0, bd2, bi2); ce(bd1, bi1, bd3, bi3);
    ce(bd0, bi0, bd1, bi1); ce(bd2, bi2, bd3, bi3);
  }

  if (lane == 0) {
    ((int4*)nbr)[b * POOL_N + qid] = make_int4(bi0, bi1, bi2, bi3);
    float* ov = outV + ((size_t)b * POOL_N + qid) * 3;   // fused vertices_pool
    ov[0] = qx; ov[1] = qy; ov[2] = qz;
  }
}

// ---------------- Kernel 3: feature max-pool over 4 neighbors (exact) -----
__global__ __launch_bounds__(256) void pool_kernel(const float* __restrict__ fm,
                                                   const int* __restrict__ nbr,
                                                   float* __restrict__ outF) {
  const int t = blockIdx.x * 256 + threadIdx.x;
  if (t >= B_N * C_N * POOL_N) return;
  const int j  = t & (POOL_N - 1);
  const int bc = t >> 10;          // b*128 + c
  const int b  = bc >> 7;
  const int4 nb = *(const int4*)(nbr + ((b * POOL_N) + j) * 4);
  const float* base = fm + (size_t)bc * V_N * 3;
  const float* p0 = base + nb.x * 3;
  const float* p1 = base + nb.y * 3;
  const float* p2 = base + nb.z * 3;
  const float* p3 = base + nb.w * 3;
  const float m0 = fmaxf(fmaxf(p0[0], p1[0]), fmaxf(p2[0], p3[0]));
  const float m1 = fmaxf(fmaxf(p0[1], p1[1]), fmaxf(p2[1], p3[1]));
  const float m2 = fmaxf(fmaxf(p0[2], p1[2]), fmaxf(p2[2], p3[2]));
  float* o = outF + (size_t)t * 3;
  o[0] = m0; o[1] = m1; o[2] = m2;
}

extern "C" void kernel_launch(void* const* d_in, const int* in_sizes, int n_in,
                              void* d_out, int out_size, void* d_ws, size_t ws_size,
                              hipStream_t stream) {
  const float* verts = (const float*)d_in[0];   // (4, 4096, 3) f32
  const float* fm    = (const float*)d_in[1];   // (4, 128, 4096, 3) f32
  float* out = (float*)d_out;                   // 12288 + 1572864 f32
  int* perm = (int*)d_ws;                       // [4096]
  int* nbr  = perm + V_N;                       // [4*1024*4], 16-B aligned

  // Derive both rounds' subkeys on host (deterministic, baked as kernel args).
  // key(42) = (0, 42); foldlike split: next = TF(key,(0,0)), sub = TF(key,(0,1)).
  uint32_t k0 = 0u, k1 = 42u, sub0[2], sub1[2];
  for (int r = 0; r < 2; ++r) {
    uint32_t n0, n1, s0, s1;
    tf2x32(k0, k1, 0u, 0u, n0, n1);
    tf2x32(k0, k1, 0u, 1u, s0, s1);
    sub0[r] = s0; sub1[r] = s1; k0 = n0; k1 = n1;
  }

  perm_kernel<<<V_N / 16, 256, 0, stream>>>(sub0[0], sub1[0], sub0[1], sub1[1], perm);
  knn_kernel<<<dim3(POOL_N / 8, B_N), 512, 0, stream>>>(verts, perm, nbr, out);
  pool_kernel<<<(B_N * C_N * POOL_N + 255) / 256, 256, 0, stream>>>(fm, nbr, out + B_N * POOL_N * 3);
}

// Round 5
// 45.532 us; speedup vs baseline: 7.4442x; 1.2585x over previous
//
#include <hip/hip_runtime.h>
#include <stdint.h>

#define V_N    4096
#define B_N    4
#define C_N    128
#define POOL_N 1024   // V_N / POOLING_RATE
#define K_NBR  4

// ---------------- Threefry-2x32 (20 rounds), exactly as JAX lowers it ----
__host__ __device__ __forceinline__ void tf2x32(uint32_t k0, uint32_t k1,
                                                uint32_t x0, uint32_t x1,
                                                uint32_t& o0, uint32_t& o1) {
  uint32_t ks[3] = {k0, k1, k0 ^ k1 ^ 0x1BD11BDAu};
  const int R[5][4] = {{13,15,26,6},{17,29,16,24},{13,15,26,6},{17,29,16,24},{13,15,26,6}};
  x0 += ks[0]; x1 += ks[1];
#pragma unroll
  for (int g = 0; g < 5; ++g) {
#pragma unroll
    for (int r = 0; r < 4; ++r) {
      x0 += x1;
      const int rot = R[g][r];
      x1 = (x1 << rot) | (x1 >> (32 - rot));
      x1 ^= x0;
    }
    x0 += ks[(g + 1) % 3];
    x1 += ks[(g + 2) % 3] + (uint32_t)(g + 1);
  }
  o0 = x0; o1 = x1;
}

// ---------------- Kernel 1: full 2-round permutation, one launch ----------
// Stable sort of distinct (bits, idx) pairs == counting sort by rank, and
// final[r2(r1(i))] = i, where r1/r2 depend only on the fixed keys.
__global__ __launch_bounds__(256) void perm_kernel(uint32_t s10, uint32_t s11,
                                                   uint32_t s20, uint32_t s21,
                                                   int* __restrict__ final_perm) {
  __shared__ uint32_t b1[V_N];        // 16 KB round-1 bits
  __shared__ uint32_t b2[V_N];        // 16 KB round-2 bits
  __shared__ int partial[16][16];     // [seg][q]
  __shared__ int pbuf[16];
  __shared__ uint32_t kbuf[16];
  const int tid = threadIdx.x;

#pragma unroll
  for (int w = 0; w < 16; ++w) {
    const int i = tid + 256 * w;
    uint32_t h, l;
    tf2x32(s10, s11, 0u, (uint32_t)i, h, l); b1[i] = h ^ l;
    tf2x32(s20, s21, 0u, (uint32_t)i, h, l); b2[i] = h ^ l;
  }
  __syncthreads();

  const int q   = tid & 15;            // element slot in block
  const int seg = tid >> 4;            // candidate segment
  const int e   = blockIdx.x * 16 + q; // element 0..4095
  const uint32_t ke = b1[e];

  int r = 0;
#pragma unroll 8
  for (int i = 0; i < 256; ++i) {
    const int m = seg + 16 * i;
    const uint32_t bm = b1[m];
    r += (bm < ke || (bm == ke && m < e)) ? 1 : 0;
  }
  partial[seg][q] = r;
  __syncthreads();
  if (tid < 16) {
    int p = 0;
#pragma unroll
    for (int s = 0; s < 16; ++s) p += partial[s][tid];
    pbuf[tid] = p;
    kbuf[tid] = b2[p];
  }
  __syncthreads();

  const int p = pbuf[q];
  const uint32_t kp = kbuf[q];
  r = 0;
#pragma unroll 8
  for (int i = 0; i < 256; ++i) {
    const int m = seg + 16 * i;
    const uint32_t bm = b2[m];
    r += (bm < kp || (bm == kp && m < p)) ? 1 : 0;
  }
  partial[seg][q] = r;
  __syncthreads();
  if (tid < 16) {
    int r2 = 0;
#pragma unroll
    for (int s = 0; s < 16; ++s) r2 += partial[s][tid];
    final_perm[r2] = blockIdx.x * 16 + tid;
  }
}

// ---------------- Kernel 2: kNN, one query per WAVE + shuffle merge -------
// dist replicates reference fp32 rounding exactly:
//   quad  = (x*x + y*y) + z*z ; inner = fmaf(z,z',fmaf(y,y',x*x'))
//   dist  = ((-2*inner) + quad_m) + quad_n
// Candidates read 4-at-a-time via 3x ds_read_b128 (packed xyz), scanned in
// ascending m so the strict-< insertion keeps lax.top_k tie-break semantics.
__device__ __forceinline__ bool lexlt(float d1, int i1, float d2, int i2) {
  return d1 < d2 || (d1 == d2 && i1 < i2);
}
__device__ __forceinline__ void ce(float& da, int& ia, float& db, int& ib) {
  if (!lexlt(da, ia, db, ib)) {
    float td = da; da = db; db = td;
    int   ti = ia; ia = ib; ib = ti;
  }
}

__global__ __launch_bounds__(512) void knn_kernel(const float* __restrict__ verts,
                                                  const int* __restrict__ perm,
                                                  int* __restrict__ nbr,
                                                  float* __restrict__ outV) {
  __shared__ float4 sv4[V_N * 3 / 4];           // 48 KB packed xyz
  const float* sv = (const float*)sv4;
  const int tid = threadIdx.x;
  const int b = blockIdx.y;
  const float4* vb4 = (const float4*)(verts + (size_t)b * V_N * 3);
#pragma unroll
  for (int w = 0; w < 6; ++w)
    sv4[tid + 512 * w] = vb4[tid + 512 * w];
  __syncthreads();

  const int lane = tid & 63;
  const int wv   = tid >> 6;                    // wave id 0..7 = query slot
  const int qid  = blockIdx.x * 8 + wv;         // 0..1023 output slot
  const int qv   = perm[qid];                   // sampled vertex index
  const float qx = sv[3 * qv], qy = sv[3 * qv + 1], qz = sv[3 * qv + 2];
  const float qq = __fadd_rn(__fadd_rn(__fmul_rn(qx, qx), __fmul_rn(qy, qy)),
                             __fmul_rn(qz, qz));

  float bd0 = 1e30f, bd1 = 1e30f, bd2 = 1e30f, bd3 = 1e30f;
  int   bi0 = -1, bi1 = -1, bi2 = -1, bi3 = -1;

#define EVAL(X, Y, Z, MC)                                                     \
  do {                                                                        \
    const float x_ = (X), y_ = (Y), z_ = (Z);                                 \
    const int mc_ = (MC);                                                     \
    const float qm_ = __fadd_rn(__fadd_rn(__fmul_rn(x_, x_),                  \
                                          __fmul_rn(y_, y_)),                 \
                                __fmul_rn(z_, z_));                           \
    const float in_ = __fmaf_rn(qz, z_, __fmaf_rn(qy, y_, __fmul_rn(qx, x_)));\
    const float dist = __fadd_rn(__fmaf_rn(-2.0f, in_, qm_), qq);             \
    if (mc_ != qv && dist < bd3) {                                            \
      if (dist < bd2) {                                                       \
        bd3 = bd2; bi3 = bi2;                                                 \
        if (dist < bd1) {                                                     \
          bd2 = bd1; bi2 = bi1;                                               \
          if (dist < bd0) { bd1 = bd0; bi1 = bi0; bd0 = dist; bi0 = mc_; }    \
          else            { bd1 = dist; bi1 = mc_; }                          \
        } else { bd2 = dist; bi2 = mc_; }                                     \
      } else { bd3 = dist; bi3 = mc_; }                                       \
    }                                                                         \
  } while (0)

#pragma unroll 4
  for (int i = 0; i < 16; ++i) {
    const int base = lane + 64 * i;             // 4 candidates per lane-iter
    const float4 c0 = sv4[3 * base + 0];
    const float4 c1 = sv4[3 * base + 1];
    const float4 c2 = sv4[3 * base + 2];
    const int m0 = 4 * base;
    EVAL(c0.x, c0.y, c0.z, m0 + 0);
    EVAL(c0.w, c1.x, c1.y, m0 + 1);
    EVAL(c1.z, c1.w, c2.x, m0 + 2);
    EVAL(c2.y, c2.z, c2.w, m0 + 3);
  }
#undef EVAL

  // 6-stage butterfly: merge two sorted 4-lists -> sorted top-4 (bitonic).
#pragma unroll
  for (int off = 1; off <= 32; off <<= 1) {
    const float e0 = __shfl_xor(bd0, off), e1 = __shfl_xor(bd1, off);
    const float e2 = __shfl_xor(bd2, off), e3 = __shfl_xor(bd3, off);
    const int   f0 = __shfl_xor(bi0, off), f1 = __shfl_xor(bi1, off);
    const int   f2 = __shfl_xor(bi2, off), f3 = __shfl_xor(bi3, off);
    const bool c0 = lexlt(bd0, bi0, e3, f3); bd0 = c0 ? bd0 : e3; bi0 = c0 ? bi0 : f3;
    const bool c1 = lexlt(bd1, bi1, e2, f2); bd1 = c1 ? bd1 : e2; bi1 = c1 ? bi1 : f2;
    const bool c2 = lexlt(bd2, bi2, e1, f1); bd2 = c2 ? bd2 : e1; bi2 = c2 ? bi2 : f1;
    const bool c3 = lexlt(bd3, bi3, e0, f0); bd3 = c3 ? bd3 : e0; bi3 = c3 ? bi3 : f0;
    ce(bd0, bi0, bd2, bi2); ce(bd1, bi1, bd3, bi3);
    ce(bd0, bi0, bd1, bi1); ce(bd2, bi2, bd3, bi3);
  }

  if (lane == 0) {
    ((int4*)nbr)[b * POOL_N + qid] = make_int4(bi0, bi1, bi2, bi3);
    float* ov = outV + ((size_t)b * POOL_N + qid) * 3;   // fused vertices_pool
    ov[0] = qx; ov[1] = qy; ov[2] = qz;
  }
}

// ---------------- Kernel 3: feature max-pool, LDS-staged (b,c) slice ------
// One block per (b,c): coalesced float4 read of the 48 KB slice into LDS,
// gather+max from LDS, contiguous float4 stores. Exact max of 4 floats.
__global__ __launch_bounds__(256) void pool_kernel(const float* __restrict__ fm,
                                                   const int* __restrict__ nbr,
                                                   float* __restrict__ outF) {
  __shared__ float4 sf4[V_N * 3 / 4];           // 48 KB
  const float* sf = (const float*)sf4;
  const int tid = threadIdx.x;
  const int bc = blockIdx.x;                    // 0..511 = b*128 + c
  const int b  = bc >> 7;
  const float4* src = (const float4*)(fm + (size_t)bc * V_N * 3);
#pragma unroll
  for (int w = 0; w < 12; ++w)
    sf4[tid + 256 * w] = src[tid + 256 * w];
  __syncthreads();

  const int j0 = tid * 4;                       // 4 outputs per thread
  const int4* nb4 = (const int4*)(nbr) + b * POOL_N + j0;

  const int4 n0 = nb4[0];
  const float* a0 = sf + n0.x * 3; const float* a1 = sf + n0.y * 3;
  const float* a2 = sf + n0.z * 3; const float* a3 = sf + n0.w * 3;
  const float r00 = fmaxf(fmaxf(a0[0], a1[0]), fmaxf(a2[0], a3[0]));
  const float r01 = fmaxf(fmaxf(a0[1], a1[1]), fmaxf(a2[1], a3[1]));
  const float r02 = fmaxf(fmaxf(a0[2], a1[2]), fmaxf(a2[2], a3[2]));

  const int4 n1 = nb4[1];
  const float* b0 = sf + n1.x * 3; const float* b1 = sf + n1.y * 3;
  const float* b2 = sf + n1.z * 3; const float* b3 = sf + n1.w * 3;
  const float r10 = fmaxf(fmaxf(b0[0], b1[0]), fmaxf(b2[0], b3[0]));
  const float r11 = fmaxf(fmaxf(b0[1], b1[1]), fmaxf(b2[1], b3[1]));
  const float r12 = fmaxf(fmaxf(b0[2], b1[2]), fmaxf(b2[2], b3[2]));

  const int4 n2 = nb4[2];
  const float* c0 = sf + n2.x * 3; const float* c1 = sf + n2.y * 3;
  const float* c2 = sf + n2.z * 3; const float* c3 = sf + n2.w * 3;
  const float r20 = fmaxf(fmaxf(c0[0], c1[0]), fmaxf(c2[0], c3[0]));
  const float r21 = fmaxf(fmaxf(c0[1], c1[1]), fmaxf(c2[1], c3[1]));
  const float r22 = fmaxf(fmaxf(c0[2], c1[2]), fmaxf(c2[2], c3[2]));

  const int4 n3 = nb4[3];
  const float* d0 = sf + n3.x * 3; const float* d1 = sf + n3.y * 3;
  const float* d2 = sf + n3.z * 3; const float* d3 = sf + n3.w * 3;
  const float r30 = fmaxf(fmaxf(d0[0], d1[0]), fmaxf(d2[0], d3[0]));
  const float r31 = fmaxf(fmaxf(d0[1], d1[1]), fmaxf(d2[1], d3[1]));
  const float r32 = fmaxf(fmaxf(d0[2], d1[2]), fmaxf(d2[2], d3[2]));

  float4* dst = (float4*)(outF + (size_t)bc * POOL_N * 3 + (size_t)j0 * 3);
  dst[0] = make_float4(r00, r01, r02, r10);
  dst[1] = make_float4(r11, r12, r20, r21);
  dst[2] = make_float4(r22, r30, r31, r32);
}

extern "C" void kernel_launch(void* const* d_in, const int* in_sizes, int n_in,
                              void* d_out, int out_size, void* d_ws, size_t ws_size,
                              hipStream_t stream) {
  const float* verts = (const float*)d_in[0];   // (4, 4096, 3) f32
  const float* fm    = (const float*)d_in[1];   // (4, 128, 4096, 3) f32
  float* out = (float*)d_out;                   // 12288 + 1572864 f32
  int* perm = (int*)d_ws;                       // [4096]
  int* nbr  = perm + V_N;                       // [4*1024*4], 16-B aligned

  // Derive both rounds' subkeys on host (deterministic, baked as kernel args).
  // key(42) = (0, 42); foldlike split: next = TF(key,(0,0)), sub = TF(key,(0,1)).
  uint32_t k0 = 0u, k1 = 42u, sub0[2], sub1[2];
  for (int r = 0; r < 2; ++r) {
    uint32_t n0, n1, s0, s1;
    tf2x32(k0, k1, 0u, 0u, n0, n1);
    tf2x32(k0, k1, 0u, 1u, s0, s1);
    sub0[r] = s0; sub1[r] = s1; k0 = n0; k1 = n1;
  }

  perm_kernel<<<V_N / 16, 256, 0, stream>>>(sub0[0], sub1[0], sub0[1], sub1[1], perm);
  knn_kernel<<<dim3(POOL_N / 8, B_N), 512, 0, stream>>>(verts, perm, nbr, out);
  pool_kernel<<<B_N * C_N, 256, 0, stream>>>(fm, nbr, out + B_N * POOL_N * 3);
}